// Round 12
// baseline (363.899 us; speedup 1.0000x reference)
//
#include <hip/hip_runtime.h>
#include <hip/hip_bf16.h>
#include <cstdint>
#include <cstddef>

typedef __bf16 bf16_t;
typedef __bf16 bf16x8 __attribute__((ext_vector_type(8)));
typedef __bf16 bf16x4v __attribute__((ext_vector_type(4)));
typedef __bf16 bf16x2v __attribute__((ext_vector_type(2)));
typedef float f32x4 __attribute__((ext_vector_type(4)));
typedef float f32x16 __attribute__((ext_vector_type(16)));
typedef uint32_t u32x4 __attribute__((ext_vector_type(4)));
typedef uint32_t u32x2 __attribute__((ext_vector_type(2)));

#define DEVI static __device__ __forceinline__

// async global->LDS, 16B per lane. LDS dest must be wave-uniform base + lane*16.
DEVI void gl_lds16(const void* g, void* l) {
    __builtin_amdgcn_global_load_lds((const __attribute__((address_space(1))) void*)g,
                                     (__attribute__((address_space(3))) void*)l, 16, 0, 0);
}

DEVI float fexp2(float x) {
#if __has_builtin(__builtin_amdgcn_exp2f)
    return __builtin_amdgcn_exp2f(x);
#else
    return __expf(x * 0.6931471805599453f);
#endif
}

DEVI uint32_t pkbf16(float a, float b) {
    bf16x2v t;
    t[0] = (bf16_t)a;
    t[1] = (bf16_t)b;
    return __builtin_bit_cast(uint32_t, t);
}

// ---------------- cast fp32 -> bf16 (3 tensors in one launch) ----------------
__global__ __launch_bounds__(256) void castk(const float* __restrict__ i0, const float* __restrict__ i1,
                                             const float* __restrict__ i2, bf16_t* __restrict__ o0,
                                             bf16_t* __restrict__ o1, bf16_t* __restrict__ o2) {
    const float* in = blockIdx.y == 0 ? i0 : blockIdx.y == 1 ? i1 : i2;
    bf16_t* out = blockIdx.y == 0 ? o0 : blockIdx.y == 1 ? o1 : o2;
    size_t i = ((size_t)blockIdx.x * 256 + threadIdx.x) * 4;
    float4 v = *(const float4*)(in + i);
    bf16x4v o;
    o[0] = (bf16_t)v.x; o[1] = (bf16_t)v.y; o[2] = (bf16_t)v.z; o[3] = (bf16_t)v.w;
    *(bf16x4v*)(out + i) = o;
}

// ---------------- transpose+cast weight 1024x1024: Wt[n][k] = W[k][n] ----------------
__global__ __launch_bounds__(256) void wtrans(const float* __restrict__ W0, const float* __restrict__ W1,
                                              const float* __restrict__ W2, const float* __restrict__ W3,
                                              bf16_t* __restrict__ O0, bf16_t* __restrict__ O1,
                                              bf16_t* __restrict__ O2, bf16_t* __restrict__ O3) {
    const float* W; bf16_t* O;
    switch (blockIdx.z) {
        case 0: W = W0; O = O0; break;
        case 1: W = W1; O = O1; break;
        case 2: W = W2; O = O2; break;
        default: W = W3; O = O3; break;
    }
    __shared__ float t[32][33];
    int tx = threadIdx.x & 31, ty = threadIdx.x >> 5;   // 32x8
    int bx = blockIdx.x * 32, by = blockIdx.y * 32;     // bx: n, by: k
#pragma unroll
    for (int yy = 0; yy < 4; ++yy)
        t[ty + yy * 8][tx] = W[(size_t)(by + ty + yy * 8) * 1024 + bx + tx];
    __syncthreads();
#pragma unroll
    for (int yy = 0; yy < 4; ++yy)
        O[(size_t)(bx + ty + yy * 8) * 1024 + by + tx] = (bf16_t)t[tx][ty + yy * 8];
}

// ---------------- RoPE tables: ctab/stab [2048][32] fp32 ----------------
__global__ __launch_bounds__(256) void rope_tab(float* __restrict__ ctab, float* __restrict__ stab) {
    int idx = blockIdx.x * 256 + threadIdx.x;   // 65536 = 2048*32
    int s = idx >> 5, i = idx & 31;
    float inv = 1.0f / powf(10000.0f, (float)i * (1.0f / 32.0f));
    float f = (float)s * inv;
    ctab[idx] = cosf(f);
    stab[idx] = sinf(f);
}

// ---------------- fused QKV projection GEMM (grid.z selects Q/K/V) ----------------
// Grid (64,8,3): blockIdx.x = M-row tile; linear%8 = x%8, so the 8 N-tiles of one M-row
// share an XCD's L2 (A row-tile fetched once per XCD).
// BK=64: 16 K-iterations — halves the per-iter vmcnt(0)+barrier drain (r7: WIN).
// T2 swizzle for 128B rows: 16B-chunk index XOR'd with row&7, inverse-swizzled GLOBAL
// source + linear gl_lds16 dest + swizzled read. Conflict-free frag reads.
__global__ __launch_bounds__(256) void gemm_qkv(const bf16_t* __restrict__ Xq, const bf16_t* __restrict__ Xk,
                                                const bf16_t* __restrict__ Xv, const bf16_t* __restrict__ Wqt,
                                                const bf16_t* __restrict__ Wkt, const bf16_t* __restrict__ Wvt,
                                                const float* __restrict__ bqp, const float* __restrict__ bkp,
                                                const float* __restrict__ bvp, bf16_t* __restrict__ Qo,
                                                bf16_t* __restrict__ Ko, bf16_t* __restrict__ Vo,
                                                const float* __restrict__ ctab, const float* __restrict__ stab) {
    constexpr int K = 1024;
    const int z = blockIdx.z;
    const bf16_t* A  = z == 0 ? Xq : z == 1 ? Xk : Xv;
    const bf16_t* Bt = z == 0 ? Wqt : z == 1 ? Wkt : Wvt;
    const float* bias = z == 0 ? bqp : z == 1 ? bkp : bvp;
    bf16_t* O = z == 0 ? Qo : z == 1 ? Ko : Vo;
    const float scale = z == 0 ? 0.18033688011112042f : 1.0f;   // log2(e)/8 folded into Q

    __shared__ alignas(16) bf16_t As[128 * 64];   // 16KB
    __shared__ alignas(16) bf16_t Bs[128 * 64];   // 16KB
    const int tid = threadIdx.x;
    const int w = tid >> 6, lane = tid & 63, c = lane & 15, qd = lane >> 4;
    const int wm = w >> 1, wn = w & 1;
    const int c7 = c & 7;                         // row&7 of every frag-read row
    const int m0 = blockIdx.x * 128, n0 = blockIdx.y * 128;
    f32x4 acc[4][4] = {};
    for (int kt = 0; kt < K / 64; ++kt) {
#pragma unroll
        for (int l = 0; l < 4; ++l) {
            int slot = l * 256 + tid;             // 16B slots: row = slot>>3, chunk = slot&7
            int row = slot >> 3, ch = slot & 7;
            int sch = ch ^ (row & 7);             // inverse-swizzled source, linear dest
            gl_lds16(A + (size_t)(m0 + row) * K + kt * 64 + sch * 8, (char*)As + (size_t)slot * 16);
            gl_lds16(Bt + (size_t)(n0 + row) * K + kt * 64 + sch * 8, (char*)Bs + (size_t)slot * 16);
        }
        __syncthreads();
#pragma unroll
        for (int kk = 0; kk < 2; ++kk) {
            const int cs8 = (kk * 4 + qd) ^ c7;   // swizzled chunk for k-slice kk
            bf16x8 af[4], bfr[4];
#pragma unroll
            for (int i = 0; i < 4; ++i)
                af[i] = *(const bf16x8*)&As[(wm * 64 + i * 16 + c) * 64 + cs8 * 8];
#pragma unroll
            for (int j = 0; j < 4; ++j)
                bfr[j] = *(const bf16x8*)&Bs[(wn * 64 + j * 16 + c) * 64 + cs8 * 8];
#pragma unroll
            for (int i = 0; i < 4; ++i)
#pragma unroll
                for (int j = 0; j < 4; ++j)
                    acc[i][j] = __builtin_amdgcn_mfma_f32_16x16x32_bf16(af[i], bfr[j], acc[i][j], 0, 0, 0);
        }
        __syncthreads();
    }
    const int mb = m0 + wm * 64;
    const int nb = n0 + wn * 64;   // head-aligned (64): nb>>6 = head
    const int h = nb >> 6;
    if (z == 2) {
        // V: store transposed Vt[b,h,d,s], packing 4 consecutive s per store
#pragma unroll
        for (int i = 0; i < 4; ++i) {
            int m = mb + i * 16 + qd * 4;     // 4 consecutive s at r=0..3, same b
            int b = m >> 11, s = m & 2047;
#pragma unroll
            for (int j = 0; j < 4; ++j) {
                int d = j * 16 + c;
                float bv = bias[nb + d];
                bf16x4v v4;
#pragma unroll
                for (int r = 0; r < 4; ++r) v4[r] = (bf16_t)(acc[i][j][r] + bv);
                *(bf16x4v*)(O + ((size_t)(b * 16 + h) * 64 + d) * 2048 + s) = v4;
            }
        }
    } else {
#pragma unroll
        for (int i = 0; i < 4; ++i)
#pragma unroll
            for (int jh = 0; jh < 2; ++jh) {
                int d1 = jh * 16 + c;                 // [0,32)
                float b1 = bias[nb + d1];
                float b2 = bias[nb + d1 + 32];
#pragma unroll
                for (int r = 0; r < 4; ++r) {
                    int m = mb + i * 16 + qd * 4 + r;
                    int b = m >> 11, s = m & 2047;
                    float v1 = acc[i][jh][r] + b1;
                    float v2 = acc[i][jh + 2][r] + b2;
                    float ct = ctab[s * 32 + d1];
                    float st = stab[s * 32 + d1];
                    size_t base = ((size_t)(b * 16 + h) * 2048 + s) * 64;
                    O[base + d1]      = (bf16_t)((v1 * ct - v2 * st) * scale);
                    O[base + d1 + 32] = (bf16_t)((v2 * ct + v1 * st) * scale);
                }
            }
    }
}

// ---------------- out-proj GEMM: fp32 store [m,n] + bias. Grid (64,8), x = M-tile ----------------
// Same BK=64 + row&7 chunk swizzle as gemm_qkv.
__global__ __launch_bounds__(256) void gemm_out(const bf16_t* __restrict__ A, const bf16_t* __restrict__ Bt,
                                                const float* __restrict__ bias, float* __restrict__ O) {
    constexpr int K = 1024, N = 1024;
    __shared__ alignas(16) bf16_t As[128 * 64];
    __shared__ alignas(16) bf16_t Bs[128 * 64];
    const int tid = threadIdx.x;
    const int w = tid >> 6, lane = tid & 63, c = lane & 15, qd = lane >> 4;
    const int wm = w >> 1, wn = w & 1;
    const int c7 = c & 7;
    const int m0 = blockIdx.x * 128, n0 = blockIdx.y * 128;
    f32x4 acc[4][4] = {};
    for (int kt = 0; kt < K / 64; ++kt) {
#pragma unroll
        for (int l = 0; l < 4; ++l) {
            int slot = l * 256 + tid;
            int row = slot >> 3, ch = slot & 7;
            int sch = ch ^ (row & 7);
            gl_lds16(A + (size_t)(m0 + row) * K + kt * 64 + sch * 8, (char*)As + (size_t)slot * 16);
            gl_lds16(Bt + (size_t)(n0 + row) * K + kt * 64 + sch * 8, (char*)Bs + (size_t)slot * 16);
        }
        __syncthreads();
#pragma unroll
        for (int kk = 0; kk < 2; ++kk) {
            const int cs8 = (kk * 4 + qd) ^ c7;
            bf16x8 af[4], bfr[4];
#pragma unroll
            for (int i = 0; i < 4; ++i)
                af[i] = *(const bf16x8*)&As[(wm * 64 + i * 16 + c) * 64 + cs8 * 8];
#pragma unroll
            for (int j = 0; j < 4; ++j)
                bfr[j] = *(const bf16x8*)&Bs[(wn * 64 + j * 16 + c) * 64 + cs8 * 8];
#pragma unroll
            for (int i = 0; i < 4; ++i)
#pragma unroll
                for (int j = 0; j < 4; ++j)
                    acc[i][j] = __builtin_amdgcn_mfma_f32_16x16x32_bf16(af[i], bfr[j], acc[i][j], 0, 0, 0);
        }
        __syncthreads();
    }
    const int mb = m0 + wm * 64, nb = n0 + wn * 64;
#pragma unroll
    for (int i = 0; i < 4; ++i)
#pragma unroll
        for (int j = 0; j < 4; ++j) {
            int n = nb + j * 16 + c;
            float bv = bias[n];
#pragma unroll
            for (int r = 0; r < 4; ++r) {
                int m = mb + i * 16 + qd * 4 + r;
                O[(size_t)m * N + n] = acc[i][j][r] + bv;
            }
        }
}

// ---------------- flash attention v12: deferred-PV, open-coded (T15 retry) ----------------
// r11 proved the window is VALU/latency-bound (MFMA-delete made it worse); r10 proved
// cross-block overlap never materializes (memory system re-syncs blocks). The overlap
// must come from WITHIN the wave's stream: window wi = { stage K(wi+1),V(wi); QK(wi);
// exp(wi)->pku_prod; PV(wi-1) from pku_cons } — PV's 8 MFMAs are independent of this
// window's QK/exp and dual-pipe with the exp chain. v9's spill came from the
// lambda/array-reference form (VGPR pinned 64 + scratch): v12 is OPEN-CODED via a
// macro with compile-time parity/flags and the two pku arrays named directly; all
// indices are unrolled constants (rule #20). v11's VALU row-sums retained (frees
// acc_l; persistent state delta vs v7 = 0). QK split per-sb to halve st liveness.
// LDS: K dbuf [0,16K), V dbuf [16K,32K); same barrier semantics as v7 (proven).
__global__ __launch_bounds__(256, 4) void attn(const bf16_t* __restrict__ Q, const bf16_t* __restrict__ K,
                                               const bf16_t* __restrict__ Vt, bf16_t* __restrict__ ctx) {
    constexpr int S = 2048, NT = S / 64;
    __shared__ alignas(16) char smem[32768];
    const int tid = threadIdx.x, w = tid >> 6, lane = tid & 63;
    const int lo5 = lane & 31, hi = lane >> 5;
    const int rm = (lo5 >> 1) & 7;              // read-side swizzle mask (row mod 16)/2
    const int bh = blockIdx.x, q0 = blockIdx.y * 128;
    const bf16_t* Qb = Q + (size_t)bh * S * 64 + (size_t)q0 * 64;
    const bf16_t* Kb = K + (size_t)bh * S * 64;
    const bf16_t* Vb = Vt + (size_t)bh * 64 * S;
    // ---- stage Q (128x64 = 16KB), read B-frags, recycle region ----
#pragma unroll
    for (int l = 0; l < 4; ++l) {
        int slot = l * 256 + tid;               // 16B slots
        int row = slot >> 3, ch = slot & 7;
        int sch = ch ^ ((row >> 1) & 7);
        gl_lds16(Qb + (size_t)row * 64 + sch * 8, smem + (size_t)slot * 16);
    }
    __syncthreads();
    bf16x8 qf[4];                               // [kc]: B[n=q=w*32+lo5][k=d=kc*16+hi*8+j]
    {
        const bf16_t* Qs = (const bf16_t*)smem;
#pragma unroll
        for (int kc = 0; kc < 4; ++kc)
            qf[kc] = *(const bf16x8*)&Qs[(size_t)(w * 32 + lo5) * 64 + ((kc * 2 + hi) ^ rm) * 8];
    }
    __syncthreads();                            // all waves done reading Q
    auto stageK = [&](int kt, int buf) {
        const int s0 = kt * 64;
        char* kbase = smem + buf * 8192;
#pragma unroll
        for (int l = 0; l < 2; ++l) {
            int slot = l * 256 + tid;
            int row = slot >> 3, ch = slot & 7;
            int sch = ch ^ ((row >> 1) & 7);
            gl_lds16(Kb + (size_t)(s0 + row) * 64 + sch * 8, kbase + (size_t)slot * 16);
        }
    };
    auto stageV = [&](int kt, int buf) {
        const int s0 = kt * 64;
        char* vbase = smem + 16384 + buf * 8192;
#pragma unroll
        for (int l = 0; l < 2; ++l) {
            int slot = l * 256 + tid;
            int row = slot >> 3, ch = slot & 7;
            int sch = ch ^ ((row >> 1) & 7);
            gl_lds16(Vb + (size_t)row * S + s0 + sch * 8, vbase + (size_t)slot * 16);
        }
    };
    f32x16 acc_o[2] = {};                       // [db]
    float ls0 = 0.0f, ls1 = 0.0f;               // per-lane row-sum partials (q = lo5)
    const f32x16 Z16 = {};
    uint32_t pkuA[2][8], pkuB[2][8];
    stageK(0, 0);
    __syncthreads();                            // K(0) resident

// One pipeline window. PAR, DO_QK, DO_PV, STAGE_K are compile-time at each call site;
// CONS/PROD are the pku array NAMES (no runtime binding). All loops fully unrolled.
#define ATTN_WIN(WI, PAR, DO_QK, DO_PV, STAGE_K, CONS, PROD)                              \
    do {                                                                                   \
        if (STAGE_K) stageK((WI) + 1, (PAR) ^ 1);                                          \
        if (DO_QK) stageV((WI), (PAR));                                                    \
        const bf16_t* KsC = (const bf16_t*)(smem + (PAR) * 8192);                          \
        const bf16_t* VsC = (const bf16_t*)(smem + 16384 + ((PAR) ^ 1) * 8192);            \
        f32x16 st0, st1;                                                                   \
        if (DO_QK) {                                                                       \
            _Pragma("unroll")                                                              \
            for (int kc = 0; kc < 4; ++kc) {                                               \
                bf16x8 kf = *(const bf16x8*)&KsC[(size_t)lo5 * 64 + ((kc * 2 + hi) ^ rm) * 8]; \
                st0 = __builtin_amdgcn_mfma_f32_32x32x16_bf16(kf, qf[kc], kc == 0 ? Z16 : st0, 0, 0, 0); \
            }                                                                              \
            _Pragma("unroll")                                                              \
            for (int u = 0; u < 8; ++u) {                                                  \
                float e0 = fexp2(st0[2 * u]);                                              \
                float e1 = fexp2(st0[2 * u + 1]);                                          \
                PROD[0][u] = pkbf16(e0, e1);                                               \
                if (u & 1) ls1 += e0 + e1; else ls0 += e0 + e1;                            \
            }                                                                              \
        }                                                                                  \
        if (DO_PV) {                                                                       \
            _Pragma("unroll")                                                              \
            for (int skc = 0; skc < 2; ++skc) {                                            \
                bf16x8 vf0 = *(const bf16x8*)&VsC[(size_t)lo5 * 64 + ((skc * 2 + hi) ^ rm) * 8];        \
                bf16x8 vf1 = *(const bf16x8*)&VsC[(size_t)(32 + lo5) * 64 + ((skc * 2 + hi) ^ rm) * 8]; \
                const int b = skc * 4;                                                     \
                u32x2 r02 = __builtin_amdgcn_permlane32_swap(CONS[0][b + 0], CONS[0][b + 2], false, false); \
                u32x2 r13 = __builtin_amdgcn_permlane32_swap(CONS[0][b + 1], CONS[0][b + 3], false, false); \
                u32x4 av = {r02[0], r13[0], r02[1], r13[1]};                               \
                bf16x8 af = __builtin_bit_cast(bf16x8, av);                                \
                acc_o[0] = __builtin_amdgcn_mfma_f32_32x32x16_bf16(af, vf0, acc_o[0], 0, 0, 0); \
                acc_o[1] = __builtin_amdgcn_mfma_f32_32x32x16_bf16(af, vf1, acc_o[1], 0, 0, 0); \
            }                                                                              \
        }                                                                                  \
        if (DO_QK) {                                                                       \
            _Pragma("unroll")                                                              \
            for (int kc = 0; kc < 4; ++kc) {                                               \
                bf16x8 kf = *(const bf16x8*)&KsC[(size_t)(32 + lo5) * 64 + ((kc * 2 + hi) ^ rm) * 8]; \
                st1 = __builtin_amdgcn_mfma_f32_32x32x16_bf16(kf, qf[kc], kc == 0 ? Z16 : st1, 0, 0, 0); \
            }                                                                              \
            _Pragma("unroll")                                                              \
            for (int u = 0; u < 8; ++u) {                                                  \
                float e0 = fexp2(st1[2 * u]);                                              \
                float e1 = fexp2(st1[2 * u + 1]);                                          \
                PROD[1][u] = pkbf16(e0, e1);                                               \
                if (u & 1) ls1 += e0 + e1; else ls0 += e0 + e1;                            \
            }                                                                              \
        }                                                                                  \
        if (DO_PV) {                                                                       \
            _Pragma("unroll")                                                              \
            for (int skc = 2; skc < 4; ++skc) {                                            \
                bf16x8 vf0 = *(const bf16x8*)&VsC[(size_t)lo5 * 64 + ((skc * 2 + hi) ^ rm) * 8];        \
                bf16x8 vf1 = *(const bf16x8*)&VsC[(size_t)(32 + lo5) * 64 + ((skc * 2 + hi) ^ rm) * 8]; \
                const int b = (skc & 1) * 4;                                               \
                u32x2 r02 = __builtin_amdgcn_permlane32_swap(CONS[1][b + 0], CONS[1][b + 2], false, false); \
                u32x2 r13 = __builtin_amdgcn_permlane32_swap(CONS[1][b + 1], CONS[1][b + 3], false, false); \
                u32x4 av = {r02[0], r13[0], r02[1], r13[1]};                               \
                bf16x8 af = __builtin_bit_cast(bf16x8, av);                                \
                acc_o[0] = __builtin_amdgcn_mfma_f32_32x32x16_bf16(af, vf0, acc_o[0], 0, 0, 0); \
                acc_o[1] = __builtin_amdgcn_mfma_f32_32x32x16_bf16(af, vf1, acc_o[1], 0, 0, 0); \
            }                                                                              \
        }                                                                                  \
    } while (0)

    // window 0: produce pkuA, no PV
    ATTN_WIN(0, 0, true, false, true, pkuB, pkuA);
    __syncthreads();
    for (int wi = 1; wi < NT - 1; wi += 2) {
        ATTN_WIN(wi, 1, true, true, true, pkuA, pkuB);      // odd: K buf1, V(wi)->buf1, PV(wi-1) buf0
        __syncthreads();
        ATTN_WIN(wi + 1, 0, true, true, true, pkuB, pkuA);  // even: K buf0, V->buf0, PV buf1
        __syncthreads();
    }
    // window NT-1 (=31, odd): no next-K stage
    ATTN_WIN(NT - 1, 1, true, true, false, pkuA, pkuB);
    __syncthreads();
    // drain: PV(NT-1) only, V buf1, consume pkuB
    ATTN_WIN(NT, 0, false, true, false, pkuB, pkuA);
#undef ATTN_WIN

    // ---- finalize l: combine hi halves, then gather into acc_o's q-per-r layout ----
    float lsum = ls0 + ls1;
    lsum += __shfl_xor(lsum, 32);               // lanes q and q+32 both hold full l[q=lo5]
    float linv[16];
#pragma unroll
    for (int r = 0; r < 16; ++r) {
        int qr = (r & 3) + 8 * (r >> 2) + 4 * hi;   // q-row of acc_o reg r
        linv[r] = 1.0f / __shfl(lsum, qr);          // gather l[qr] from lane qr
    }
    // epilogue: o = acc_o / l; C row = (reg&3)+8*(reg>>2)+4*hi, col = lo5
    const int b = bh >> 4, h = bh & 15;
#pragma unroll
    for (int db = 0; db < 2; ++db)
#pragma unroll
        for (int r = 0; r < 16; ++r) {
            int qrow = q0 + w * 32 + (r & 3) + 8 * (r >> 2) + 4 * hi;
            int d = db * 32 + lo5;
            float o = acc_o[db][r] * linv[r];
            ctx[((size_t)(b * 2048 + qrow)) * 1024 + (size_t)h * 64 + d] = (bf16_t)o;
        }
}

extern "C" void kernel_launch(void* const* d_in, const int* in_sizes, int n_in,
                              void* d_out, int out_size, void* d_ws, size_t ws_size,
                              hipStream_t stream) {
    (void)in_sizes; (void)n_in; (void)out_size; (void)ws_size;
    const float* query = (const float*)d_in[0];
    const float* key   = (const float*)d_in[1];
    const float* value = (const float*)d_in[2];
    const float* Wq = (const float*)d_in[3];
    const float* bq = (const float*)d_in[4];
    const float* Wk = (const float*)d_in[5];
    const float* bk = (const float*)d_in[6];
    const float* Wv = (const float*)d_in[7];
    const float* bv = (const float*)d_in[8];
    const float* Wo = (const float*)d_in[9];
    const float* bo = (const float*)d_in[10];

    const size_t SZ = (size_t)8192 * 1024;
    bf16_t* Xq = (bf16_t*)d_ws;
    bf16_t* Xk = Xq + SZ;
    bf16_t* Xv = Xk + SZ;
    bf16_t* Qb = Xv + SZ;
    bf16_t* Kb = Qb + SZ;
    bf16_t* Vtb = Kb + SZ;
    bf16_t* Wqt = Vtb + SZ;
    bf16_t* Wkt = Wqt + 1024 * 1024;
    bf16_t* Wvt = Wkt + 1024 * 1024;
    bf16_t* Wot = Wvt + 1024 * 1024;
    float* ctab = (float*)(Wot + 1024 * 1024);
    float* stab = ctab + 2048 * 32;
    bf16_t* CT = Xq;                // alias: Xq dead after projection GEMM

    castk<<<dim3(8192, 3), 256, 0, stream>>>(query, key, value, Xq, Xk, Xv);
    wtrans<<<dim3(32, 32, 4), 256, 0, stream>>>(Wq, Wk, Wv, Wo, Wqt, Wkt, Wvt, Wot);
    rope_tab<<<256, 256, 0, stream>>>(ctab, stab);
    gemm_qkv<<<dim3(64, 8, 3), 256, 0, stream>>>(Xq, Xk, Xv, Wqt, Wkt, Wvt, bq, bk, bv,
                                                 Qb, Kb, Vtb, ctab, stab);
    attn<<<dim3(64, 16), 256, 0, stream>>>(Qb, Kb, Vtb, CT);
    gemm_out<<<dim3(64, 8), 256, 0, stream>>>(CT, Wot, bo, (float*)d_out);
}

// Round 13
// 337.160 us; speedup vs baseline: 1.0793x; 1.0793x over previous
//
#include <hip/hip_runtime.h>
#include <hip/hip_bf16.h>
#include <cstdint>
#include <cstddef>

typedef __bf16 bf16_t;
typedef __bf16 bf16x8 __attribute__((ext_vector_type(8)));
typedef __bf16 bf16x4v __attribute__((ext_vector_type(4)));
typedef __bf16 bf16x2v __attribute__((ext_vector_type(2)));
typedef float f32x4 __attribute__((ext_vector_type(4)));
typedef float f32x16 __attribute__((ext_vector_type(16)));
typedef uint32_t u32x4 __attribute__((ext_vector_type(4)));
typedef uint32_t u32x2 __attribute__((ext_vector_type(2)));

#define DEVI static __device__ __forceinline__

// async global->LDS, 16B per lane. LDS dest must be wave-uniform base + lane*16.
DEVI void gl_lds16(const void* g, void* l) {
    __builtin_amdgcn_global_load_lds((const __attribute__((address_space(1))) void*)g,
                                     (__attribute__((address_space(3))) void*)l, 16, 0, 0);
}

DEVI float fexp2(float x) {
#if __has_builtin(__builtin_amdgcn_exp2f)
    return __builtin_amdgcn_exp2f(x);
#else
    return __expf(x * 0.6931471805599453f);
#endif
}

DEVI uint32_t pkbf16(float a, float b) {
    bf16x2v t;
    t[0] = (bf16_t)a;
    t[1] = (bf16_t)b;
    return __builtin_bit_cast(uint32_t, t);
}

// ---------------- cast fp32 -> bf16 (3 tensors in one launch) ----------------
__global__ __launch_bounds__(256) void castk(const float* __restrict__ i0, const float* __restrict__ i1,
                                             const float* __restrict__ i2, bf16_t* __restrict__ o0,
                                             bf16_t* __restrict__ o1, bf16_t* __restrict__ o2) {
    const float* in = blockIdx.y == 0 ? i0 : blockIdx.y == 1 ? i1 : i2;
    bf16_t* out = blockIdx.y == 0 ? o0 : blockIdx.y == 1 ? o1 : o2;
    size_t i = ((size_t)blockIdx.x * 256 + threadIdx.x) * 4;
    float4 v = *(const float4*)(in + i);
    bf16x4v o;
    o[0] = (bf16_t)v.x; o[1] = (bf16_t)v.y; o[2] = (bf16_t)v.z; o[3] = (bf16_t)v.w;
    *(bf16x4v*)(out + i) = o;
}

// ---------------- transpose+cast weight 1024x1024: Wt[n][k] = W[k][n] ----------------
__global__ __launch_bounds__(256) void wtrans(const float* __restrict__ W0, const float* __restrict__ W1,
                                              const float* __restrict__ W2, const float* __restrict__ W3,
                                              bf16_t* __restrict__ O0, bf16_t* __restrict__ O1,
                                              bf16_t* __restrict__ O2, bf16_t* __restrict__ O3) {
    const float* W; bf16_t* O;
    switch (blockIdx.z) {
        case 0: W = W0; O = O0; break;
        case 1: W = W1; O = O1; break;
        case 2: W = W2; O = O2; break;
        default: W = W3; O = O3; break;
    }
    __shared__ float t[32][33];
    int tx = threadIdx.x & 31, ty = threadIdx.x >> 5;   // 32x8
    int bx = blockIdx.x * 32, by = blockIdx.y * 32;     // bx: n, by: k
#pragma unroll
    for (int yy = 0; yy < 4; ++yy)
        t[ty + yy * 8][tx] = W[(size_t)(by + ty + yy * 8) * 1024 + bx + tx];
    __syncthreads();
#pragma unroll
    for (int yy = 0; yy < 4; ++yy)
        O[(size_t)(bx + ty + yy * 8) * 1024 + by + tx] = (bf16_t)t[tx][ty + yy * 8];
}

// ---------------- RoPE tables: ctab/stab [2048][32] fp32 ----------------
__global__ __launch_bounds__(256) void rope_tab(float* __restrict__ ctab, float* __restrict__ stab) {
    int idx = blockIdx.x * 256 + threadIdx.x;   // 65536 = 2048*32
    int s = idx >> 5, i = idx & 31;
    float inv = 1.0f / powf(10000.0f, (float)i * (1.0f / 32.0f));
    float f = (float)s * inv;
    ctab[idx] = cosf(f);
    stab[idx] = sinf(f);
}

// ---------------- fused QKV projection GEMM (grid.z selects Q/K/V) ----------------
// Grid (64,8,3): blockIdx.x = M-row tile; linear%8 = x%8, so the 8 N-tiles of one M-row
// share an XCD's L2 (A row-tile fetched once per XCD).
// BK=64: 16 K-iterations — halves the per-iter vmcnt(0)+barrier drain (r7: WIN).
// T2 swizzle for 128B rows: 16B-chunk index XOR'd with row&7, inverse-swizzled GLOBAL
// source + linear gl_lds16 dest + swizzled read. Conflict-free frag reads.
__global__ __launch_bounds__(256) void gemm_qkv(const bf16_t* __restrict__ Xq, const bf16_t* __restrict__ Xk,
                                                const bf16_t* __restrict__ Xv, const bf16_t* __restrict__ Wqt,
                                                const bf16_t* __restrict__ Wkt, const bf16_t* __restrict__ Wvt,
                                                const float* __restrict__ bqp, const float* __restrict__ bkp,
                                                const float* __restrict__ bvp, bf16_t* __restrict__ Qo,
                                                bf16_t* __restrict__ Ko, bf16_t* __restrict__ Vo,
                                                const float* __restrict__ ctab, const float* __restrict__ stab) {
    constexpr int K = 1024;
    const int z = blockIdx.z;
    const bf16_t* A  = z == 0 ? Xq : z == 1 ? Xk : Xv;
    const bf16_t* Bt = z == 0 ? Wqt : z == 1 ? Wkt : Wvt;
    const float* bias = z == 0 ? bqp : z == 1 ? bkp : bvp;
    bf16_t* O = z == 0 ? Qo : z == 1 ? Ko : Vo;
    const float scale = z == 0 ? 0.18033688011112042f : 1.0f;   // log2(e)/8 folded into Q

    __shared__ alignas(16) bf16_t As[128 * 64];   // 16KB
    __shared__ alignas(16) bf16_t Bs[128 * 64];   // 16KB
    const int tid = threadIdx.x;
    const int w = tid >> 6, lane = tid & 63, c = lane & 15, qd = lane >> 4;
    const int wm = w >> 1, wn = w & 1;
    const int c7 = c & 7;                         // row&7 of every frag-read row
    const int m0 = blockIdx.x * 128, n0 = blockIdx.y * 128;
    f32x4 acc[4][4] = {};
    for (int kt = 0; kt < K / 64; ++kt) {
#pragma unroll
        for (int l = 0; l < 4; ++l) {
            int slot = l * 256 + tid;             // 16B slots: row = slot>>3, chunk = slot&7
            int row = slot >> 3, ch = slot & 7;
            int sch = ch ^ (row & 7);             // inverse-swizzled source, linear dest
            gl_lds16(A + (size_t)(m0 + row) * K + kt * 64 + sch * 8, (char*)As + (size_t)slot * 16);
            gl_lds16(Bt + (size_t)(n0 + row) * K + kt * 64 + sch * 8, (char*)Bs + (size_t)slot * 16);
        }
        __syncthreads();
#pragma unroll
        for (int kk = 0; kk < 2; ++kk) {
            const int cs8 = (kk * 4 + qd) ^ c7;   // swizzled chunk for k-slice kk
            bf16x8 af[4], bfr[4];
#pragma unroll
            for (int i = 0; i < 4; ++i)
                af[i] = *(const bf16x8*)&As[(wm * 64 + i * 16 + c) * 64 + cs8 * 8];
#pragma unroll
            for (int j = 0; j < 4; ++j)
                bfr[j] = *(const bf16x8*)&Bs[(wn * 64 + j * 16 + c) * 64 + cs8 * 8];
#pragma unroll
            for (int i = 0; i < 4; ++i)
#pragma unroll
                for (int j = 0; j < 4; ++j)
                    acc[i][j] = __builtin_amdgcn_mfma_f32_16x16x32_bf16(af[i], bfr[j], acc[i][j], 0, 0, 0);
        }
        __syncthreads();
    }
    const int mb = m0 + wm * 64;
    const int nb = n0 + wn * 64;   // head-aligned (64): nb>>6 = head
    const int h = nb >> 6;
    if (z == 2) {
        // V: store transposed Vt[b,h,d,s], packing 4 consecutive s per store
#pragma unroll
        for (int i = 0; i < 4; ++i) {
            int m = mb + i * 16 + qd * 4;     // 4 consecutive s at r=0..3, same b
            int b = m >> 11, s = m & 2047;
#pragma unroll
            for (int j = 0; j < 4; ++j) {
                int d = j * 16 + c;
                float bv = bias[nb + d];
                bf16x4v v4;
#pragma unroll
                for (int r = 0; r < 4; ++r) v4[r] = (bf16_t)(acc[i][j][r] + bv);
                *(bf16x4v*)(O + ((size_t)(b * 16 + h) * 64 + d) * 2048 + s) = v4;
            }
        }
    } else {
#pragma unroll
        for (int i = 0; i < 4; ++i)
#pragma unroll
            for (int jh = 0; jh < 2; ++jh) {
                int d1 = jh * 16 + c;                 // [0,32)
                float b1 = bias[nb + d1];
                float b2 = bias[nb + d1 + 32];
#pragma unroll
                for (int r = 0; r < 4; ++r) {
                    int m = mb + i * 16 + qd * 4 + r;
                    int b = m >> 11, s = m & 2047;
                    float v1 = acc[i][jh][r] + b1;
                    float v2 = acc[i][jh + 2][r] + b2;
                    float ct = ctab[s * 32 + d1];
                    float st = stab[s * 32 + d1];
                    size_t base = ((size_t)(b * 16 + h) * 2048 + s) * 64;
                    O[base + d1]      = (bf16_t)((v1 * ct - v2 * st) * scale);
                    O[base + d1 + 32] = (bf16_t)((v2 * ct + v1 * st) * scale);
                }
            }
    }
}

// ---------------- out-proj GEMM: fp32 store [m,n] + bias. Grid (64,8), x = M-tile ----------------
// Same BK=64 + row&7 chunk swizzle as gemm_qkv.
__global__ __launch_bounds__(256) void gemm_out(const bf16_t* __restrict__ A, const bf16_t* __restrict__ Bt,
                                                const float* __restrict__ bias, float* __restrict__ O) {
    constexpr int K = 1024, N = 1024;
    __shared__ alignas(16) bf16_t As[128 * 64];
    __shared__ alignas(16) bf16_t Bs[128 * 64];
    const int tid = threadIdx.x;
    const int w = tid >> 6, lane = tid & 63, c = lane & 15, qd = lane >> 4;
    const int wm = w >> 1, wn = w & 1;
    const int c7 = c & 7;
    const int m0 = blockIdx.x * 128, n0 = blockIdx.y * 128;
    f32x4 acc[4][4] = {};
    for (int kt = 0; kt < K / 64; ++kt) {
#pragma unroll
        for (int l = 0; l < 4; ++l) {
            int slot = l * 256 + tid;
            int row = slot >> 3, ch = slot & 7;
            int sch = ch ^ (row & 7);
            gl_lds16(A + (size_t)(m0 + row) * K + kt * 64 + sch * 8, (char*)As + (size_t)slot * 16);
            gl_lds16(Bt + (size_t)(n0 + row) * K + kt * 64 + sch * 8, (char*)Bs + (size_t)slot * 16);
        }
        __syncthreads();
#pragma unroll
        for (int kk = 0; kk < 2; ++kk) {
            const int cs8 = (kk * 4 + qd) ^ c7;
            bf16x8 af[4], bfr[4];
#pragma unroll
            for (int i = 0; i < 4; ++i)
                af[i] = *(const bf16x8*)&As[(wm * 64 + i * 16 + c) * 64 + cs8 * 8];
#pragma unroll
            for (int j = 0; j < 4; ++j)
                bfr[j] = *(const bf16x8*)&Bs[(wn * 64 + j * 16 + c) * 64 + cs8 * 8];
#pragma unroll
            for (int i = 0; i < 4; ++i)
#pragma unroll
                for (int j = 0; j < 4; ++j)
                    acc[i][j] = __builtin_amdgcn_mfma_f32_16x16x32_bf16(af[i], bfr[j], acc[i][j], 0, 0, 0);
        }
        __syncthreads();
    }
    const int mb = m0 + wm * 64, nb = n0 + wn * 64;
#pragma unroll
    for (int i = 0; i < 4; ++i)
#pragma unroll
        for (int j = 0; j < 4; ++j) {
            int n = nb + j * 16 + c;
            float bv = bias[n];
#pragma unroll
            for (int r = 0; r < 4; ++r) {
                int m = mb + i * 16 + qd * 4 + r;
                O[(size_t)m * N + n] = acc[i][j][r] + bv;
            }
        }
}

// ---------------- flash attention v13: r9 structure + staging-address hoist ----------------
// v12/v9 deferred-PV abandoned (allocator refuses cross-barrier pku state: scratch
// traffic both times). v13 = r9's proven v7+setprio structure with ONE local change:
// stageKV's per-thread global addresses are affine in kt (K advances 4096 elem/window,
// V advances 64), so the 4 base pointers are computed ONCE and advanced by constant
// stride — removing the full 2D index math (~30-40 VALU/wave/window) from the serial
// QK->exp->PV path. No layout/sync/numerics change.
// Grid (64,16): x = bh (linear%8 -> all q-blocks of a bh on one XCD). 1024 blocks
// = 4/CU; __launch_bounds__(256,4) -> 16 waves/CU.
// Block: 4 waves x 32 q. LDS 32KB: Q tile staged transiently, frags hoisted, region
// recycled as double-buffered K/V (16KB per buffer). Swapped QK: St[s][q] = K.Q^T.
// St->PV-A transform via v_permlane32_swap_b32. V[d][s] = PV B-operand directly.
// Row-sums l via ones-B-frag MFMA. Q pre-scaled by log2(e)/8.
// 16B-chunk XOR swizzle (chunk^((row>>1)&7)) keeps b128 reads conflict-free.
__global__ __launch_bounds__(256, 4) void attn(const bf16_t* __restrict__ Q, const bf16_t* __restrict__ K,
                                               const bf16_t* __restrict__ Vt, bf16_t* __restrict__ ctx) {
    constexpr int S = 2048;
    __shared__ alignas(16) char smem[32768];   // Q stage 16KB -> [buf][K 8KB | V 8KB] x2
    const int tid = threadIdx.x, w = tid >> 6, lane = tid & 63;
    const int lo5 = lane & 31, hi = lane >> 5;
    const int rm = (lo5 >> 1) & 7;              // read-side swizzle mask (row mod 16)/2
    const int bh = blockIdx.x, q0 = blockIdx.y * 128;
    const bf16_t* Qb = Q + (size_t)bh * S * 64 + (size_t)q0 * 64;
    const bf16_t* Kb = K + (size_t)bh * S * 64;
    const bf16_t* Vb = Vt + (size_t)bh * 64 * S;
    // ---- stage Q (128x64 = 16KB), read B-frags, recycle region ----
#pragma unroll
    for (int l = 0; l < 4; ++l) {
        int slot = l * 256 + tid;               // 16B slots
        int row = slot >> 3, ch = slot & 7;
        int sch = ch ^ ((row >> 1) & 7);
        gl_lds16(Qb + (size_t)row * 64 + sch * 8, smem + (size_t)slot * 16);
    }
    __syncthreads();
    bf16x8 qf[4];                               // [kc]: B[n=q=w*32+lo5][k=d=kc*16+hi*8+j]
    {
        const bf16_t* Qs = (const bf16_t*)smem;
#pragma unroll
        for (int kc = 0; kc < 4; ++kc)
            qf[kc] = *(const bf16x8*)&Qs[(size_t)(w * 32 + lo5) * 64 + ((kc * 2 + hi) ^ rm) * 8];
    }
    __syncthreads();                            // all waves done reading Q
    // ---- per-thread staging bases (affine in kt: K += 4096, V += 64 per window) ----
    const bf16_t* kgp[2];
    const bf16_t* vgp[2];
    char* klp[2];
    char* vlp[2];
#pragma unroll
    for (int l = 0; l < 2; ++l) {
        int slot = l * 256 + tid;
        int row = slot >> 3, ch = slot & 7;
        int sch = ch ^ ((row >> 1) & 7);
        kgp[l] = Kb + (size_t)row * 64 + sch * 8;
        vgp[l] = Vb + (size_t)row * S + sch * 8;
        klp[l] = smem + (size_t)slot * 16;          // + buf*16384
        vlp[l] = smem + 8192 + (size_t)slot * 16;   // + buf*16384
    }
    auto stageKV = [&](int kt, int buf) {
#pragma unroll
        for (int l = 0; l < 2; ++l) {
            gl_lds16(kgp[l] + (size_t)kt * 4096, klp[l] + buf * 16384);
            gl_lds16(vgp[l] + (size_t)kt * 64,   vlp[l] + buf * 16384);
        }
    };
    stageKV(0, 0);
    f32x16 acc_o[2] = {};                       // [db]
    f32x16 acc_l = {};                          // row-sums (all cols equal)
    const f32x16 Z16 = {};
    bf16x8 ones;
    {
        u32x4 ov = {0x3F803F80u, 0x3F803F80u, 0x3F803F80u, 0x3F803F80u};
        ones = __builtin_bit_cast(bf16x8, ov);
    }
    __syncthreads();                            // tile 0 staged
    for (int kt = 0; kt < S / 64; ++kt) {
        const int cur = kt & 1;
        if (kt + 1 < S / 64) stageKV(kt + 1, cur ^ 1);
        const bf16_t* KsC = (const bf16_t*)(smem + cur * 16384);
        const bf16_t* VsC = (const bf16_t*)(smem + cur * 16384 + 8192);
        // St[s][q]: A=K[m=s=sb*32+lo5][k=d], B=Q
        f32x16 st[2];                           // [sb]
        __builtin_amdgcn_s_setprio(1);
#pragma unroll
        for (int kc = 0; kc < 4; ++kc) {
            bf16x8 kf[2];
#pragma unroll
            for (int sb = 0; sb < 2; ++sb)
                kf[sb] = *(const bf16x8*)&KsC[(size_t)(sb * 32 + lo5) * 64 + ((kc * 2 + hi) ^ rm) * 8];
#pragma unroll
            for (int sb = 0; sb < 2; ++sb)
                st[sb] = __builtin_amdgcn_mfma_f32_32x32x16_bf16(kf[sb], qf[kc],
                                                                 kc == 0 ? Z16 : st[sb], 0, 0, 0);
        }
        __builtin_amdgcn_s_setprio(0);
        // p = 2^st, pack s-pairs: pku[sb][u] covers s = sb*32 + 8*(u>>1) + 4*hi + 2*(u&1) + {0,1}
        uint32_t pku[2][8];
#pragma unroll
        for (int sb = 0; sb < 2; ++sb)
#pragma unroll
            for (int u = 0; u < 8; ++u)
                pku[sb][u] = pkbf16(fexp2(st[sb][2 * u]), fexp2(st[sb][2 * u + 1]));
        // PV: A = P[m=q][k=s chunk skc], B = V[n=d][k=s]; plus l via ones B-frag
        __builtin_amdgcn_s_setprio(1);
#pragma unroll
        for (int skc = 0; skc < 4; ++skc) {
            bf16x8 vf[2];
#pragma unroll
            for (int db = 0; db < 2; ++db)
                vf[db] = *(const bf16x8*)&VsC[(size_t)(db * 32 + lo5) * 64 + ((skc * 2 + hi) ^ rm) * 8];
            const int sb = skc >> 1, b = (skc & 1) * 4;
            uint32_t p0 = pku[sb][b + 0], p1 = pku[sb][b + 1];
            uint32_t p2 = pku[sb][b + 2], p3 = pku[sb][b + 3];
#if __has_builtin(__builtin_amdgcn_permlane32_swap)
            u32x2 r02 = __builtin_amdgcn_permlane32_swap(p0, p2, false, false);
            u32x2 r13 = __builtin_amdgcn_permlane32_swap(p1, p3, false, false);
            u32x4 av = {r02[0], r13[0], r02[1], r13[1]};
#else
            uint32_t send0 = hi ? p0 : p2;
            uint32_t send1 = hi ? p1 : p3;
            uint32_t recv0 = __shfl_xor(send0, 32);
            uint32_t recv1 = __shfl_xor(send1, 32);
            u32x4 av = {hi ? recv0 : p0, hi ? recv1 : p1,
                        hi ? p2 : recv0, hi ? p3 : recv1};
#endif
            bf16x8 af = __builtin_bit_cast(bf16x8, av);
            acc_l = __builtin_amdgcn_mfma_f32_32x32x16_bf16(af, ones, acc_l, 0, 0, 0);
#pragma unroll
            for (int db = 0; db < 2; ++db)
                acc_o[db] = __builtin_amdgcn_mfma_f32_32x32x16_bf16(af, vf[db], acc_o[db], 0, 0, 0);
        }
        __builtin_amdgcn_s_setprio(0);
        __syncthreads();
    }
    // epilogue: o = acc_o / acc_l (rows aligned); C row = (reg&3)+8*(reg>>2)+4*hi, col = lo5
    const int b = bh >> 4, h = bh & 15;
    float linv[16];
#pragma unroll
    for (int r = 0; r < 16; ++r) linv[r] = 1.0f / acc_l[r];
#pragma unroll
    for (int db = 0; db < 2; ++db)
#pragma unroll
        for (int r = 0; r < 16; ++r) {
            int qrow = q0 + w * 32 + (r & 3) + 8 * (r >> 2) + 4 * hi;
            int d = db * 32 + lo5;
            float o = acc_o[db][r] * linv[r];
            ctx[((size_t)(b * 2048 + qrow)) * 1024 + (size_t)h * 64 + d] = (bf16_t)o;
        }
}

extern "C" void kernel_launch(void* const* d_in, const int* in_sizes, int n_in,
                              void* d_out, int out_size, void* d_ws, size_t ws_size,
                              hipStream_t stream) {
    (void)in_sizes; (void)n_in; (void)out_size; (void)ws_size;
    const float* query = (const float*)d_in[0];
    const float* key   = (const float*)d_in[1];
    const float* value = (const float*)d_in[2];
    const float* Wq = (const float*)d_in[3];
    const float* bq = (const float*)d_in[4];
    const float* Wk = (const float*)d_in[5];
    const float* bk = (const float*)d_in[6];
    const float* Wv = (const float*)d_in[7];
    const float* bv = (const float*)d_in[8];
    const float* Wo = (const float*)d_in[9];
    const float* bo = (const float*)d_in[10];

    const size_t SZ = (size_t)8192 * 1024;
    bf16_t* Xq = (bf16_t*)d_ws;
    bf16_t* Xk = Xq + SZ;
    bf16_t* Xv = Xk + SZ;
    bf16_t* Qb = Xv + SZ;
    bf16_t* Kb = Qb + SZ;
    bf16_t* Vtb = Kb + SZ;
    bf16_t* Wqt = Vtb + SZ;
    bf16_t* Wkt = Wqt + 1024 * 1024;
    bf16_t* Wvt = Wkt + 1024 * 1024;
    bf16_t* Wot = Wvt + 1024 * 1024;
    float* ctab = (float*)(Wot + 1024 * 1024);
    float* stab = ctab + 2048 * 32;
    bf16_t* CT = Xq;                // alias: Xq dead after projection GEMM

    castk<<<dim3(8192, 3), 256, 0, stream>>>(query, key, value, Xq, Xk, Xv);
    wtrans<<<dim3(32, 32, 4), 256, 0, stream>>>(Wq, Wk, Wv, Wo, Wqt, Wkt, Wvt, Wot);
    rope_tab<<<256, 256, 0, stream>>>(ctab, stab);
    gemm_qkv<<<dim3(64, 8, 3), 256, 0, stream>>>(Xq, Xk, Xv, Wqt, Wkt, Wvt, bq, bk, bv,
                                                 Qb, Kb, Vtb, ctab, stab);
    attn<<<dim3(64, 16), 256, 0, stream>>>(Qb, Kb, Vtb, CT);
    gemm_out<<<dim3(64, 8), 256, 0, stream>>>(CT, Wot, bo, (float*)d_out);
}

// Round 14
// 332.319 us; speedup vs baseline: 1.0950x; 1.0146x over previous
//
#include <hip/hip_runtime.h>
#include <hip/hip_bf16.h>
#include <cstdint>
#include <cstddef>

typedef __bf16 bf16_t;
typedef __bf16 bf16x8 __attribute__((ext_vector_type(8)));
typedef __bf16 bf16x4v __attribute__((ext_vector_type(4)));
typedef __bf16 bf16x2v __attribute__((ext_vector_type(2)));
typedef float f32x4 __attribute__((ext_vector_type(4)));
typedef float f32x16 __attribute__((ext_vector_type(16)));
typedef uint32_t u32x4 __attribute__((ext_vector_type(4)));
typedef uint32_t u32x2 __attribute__((ext_vector_type(2)));

#define DEVI static __device__ __forceinline__

// async global->LDS, 16B per lane. LDS dest must be wave-uniform base + lane*16.
DEVI void gl_lds16(const void* g, void* l) {
    __builtin_amdgcn_global_load_lds((const __attribute__((address_space(1))) void*)g,
                                     (__attribute__((address_space(3))) void*)l, 16, 0, 0);
}

DEVI float fexp2(float x) {
#if __has_builtin(__builtin_amdgcn_exp2f)
    return __builtin_amdgcn_exp2f(x);
#else
    return __expf(x * 0.6931471805599453f);
#endif
}

DEVI uint32_t pkbf16(float a, float b) {
    bf16x2v t;
    t[0] = (bf16_t)a;
    t[1] = (bf16_t)b;
    return __builtin_bit_cast(uint32_t, t);
}

// ---------------- cast fp32 -> bf16 (3 tensors in one launch) ----------------
__global__ __launch_bounds__(256) void castk(const float* __restrict__ i0, const float* __restrict__ i1,
                                             const float* __restrict__ i2, bf16_t* __restrict__ o0,
                                             bf16_t* __restrict__ o1, bf16_t* __restrict__ o2) {
    const float* in = blockIdx.y == 0 ? i0 : blockIdx.y == 1 ? i1 : i2;
    bf16_t* out = blockIdx.y == 0 ? o0 : blockIdx.y == 1 ? o1 : o2;
    size_t i = ((size_t)blockIdx.x * 256 + threadIdx.x) * 4;
    float4 v = *(const float4*)(in + i);
    bf16x4v o;
    o[0] = (bf16_t)v.x; o[1] = (bf16_t)v.y; o[2] = (bf16_t)v.z; o[3] = (bf16_t)v.w;
    *(bf16x4v*)(out + i) = o;
}

// ---------------- transpose+cast weight 1024x1024: Wt[n][k] = W[k][n] ----------------
__global__ __launch_bounds__(256) void wtrans(const float* __restrict__ W0, const float* __restrict__ W1,
                                              const float* __restrict__ W2, const float* __restrict__ W3,
                                              bf16_t* __restrict__ O0, bf16_t* __restrict__ O1,
                                              bf16_t* __restrict__ O2, bf16_t* __restrict__ O3) {
    const float* W; bf16_t* O;
    switch (blockIdx.z) {
        case 0: W = W0; O = O0; break;
        case 1: W = W1; O = O1; break;
        case 2: W = W2; O = O2; break;
        default: W = W3; O = O3; break;
    }
    __shared__ float t[32][33];
    int tx = threadIdx.x & 31, ty = threadIdx.x >> 5;   // 32x8
    int bx = blockIdx.x * 32, by = blockIdx.y * 32;     // bx: n, by: k
#pragma unroll
    for (int yy = 0; yy < 4; ++yy)
        t[ty + yy * 8][tx] = W[(size_t)(by + ty + yy * 8) * 1024 + bx + tx];
    __syncthreads();
#pragma unroll
    for (int yy = 0; yy < 4; ++yy)
        O[(size_t)(bx + ty + yy * 8) * 1024 + by + tx] = (bf16_t)t[tx][ty + yy * 8];
}

// ---------------- RoPE tables: ctab/stab [2048][32] fp32 ----------------
__global__ __launch_bounds__(256) void rope_tab(float* __restrict__ ctab, float* __restrict__ stab) {
    int idx = blockIdx.x * 256 + threadIdx.x;   // 65536 = 2048*32
    int s = idx >> 5, i = idx & 31;
    float inv = 1.0f / powf(10000.0f, (float)i * (1.0f / 32.0f));
    float f = (float)s * inv;
    ctab[idx] = cosf(f);
    stab[idx] = sinf(f);
}

// ---------------- fused QKV projection GEMM (grid.z selects Q/K/V) ----------------
// Grid (64,8,3): blockIdx.x = M-row tile; linear%8 = x%8, so the 8 N-tiles of one M-row
// share an XCD's L2. BK=64 + row&7 chunk swizzle (r7 WIN, conflicts 0).
// T4-lite sync skeleton (NEW this round): true double-buffer staged TWO tiles ahead
// with raw barriers + counted vmcnt — never vmcnt(0) in-loop (r3's failure was
// __syncthreads' implicit vmcnt(0) draining the just-issued prefetch; m233: that
// drain is ~72% of the 2-barrier period). Per tile kt:
//   vmcnt(8)  -> tile kt landed, tile kt+1's 8 loads STAY in flight
//   s_barrier + sched_barrier(0)   (rule #18: fence ds_read hoisting)
//   compute from buf kt&1
//   sched_barrier(0) + s_barrier   (all waves done READING buf kt&1)
//   stage tile kt+2 -> buf kt&1    (WAR-safe: after read-done barrier; lands during
//                                   the next full tile of compute)
// LDS 64KB (2 blocks/CU): the bet is that with stalls removed, 8 waves/CU suffice.
__global__ __launch_bounds__(256) void gemm_qkv(const bf16_t* __restrict__ Xq, const bf16_t* __restrict__ Xk,
                                                const bf16_t* __restrict__ Xv, const bf16_t* __restrict__ Wqt,
                                                const bf16_t* __restrict__ Wkt, const bf16_t* __restrict__ Wvt,
                                                const float* __restrict__ bqp, const float* __restrict__ bkp,
                                                const float* __restrict__ bvp, bf16_t* __restrict__ Qo,
                                                bf16_t* __restrict__ Ko, bf16_t* __restrict__ Vo,
                                                const float* __restrict__ ctab, const float* __restrict__ stab) {
    constexpr int K = 1024, NKT = K / 64;
    const int z = blockIdx.z;
    const bf16_t* A  = z == 0 ? Xq : z == 1 ? Xk : Xv;
    const bf16_t* Bt = z == 0 ? Wqt : z == 1 ? Wkt : Wvt;
    const float* bias = z == 0 ? bqp : z == 1 ? bkp : bvp;
    bf16_t* O = z == 0 ? Qo : z == 1 ? Ko : Vo;
    const float scale = z == 0 ? 0.18033688011112042f : 1.0f;   // log2(e)/8 folded into Q

    __shared__ alignas(16) bf16_t As[2][128 * 64];   // 2 x 16KB
    __shared__ alignas(16) bf16_t Bs[2][128 * 64];   // 2 x 16KB
    const int tid = threadIdx.x;
    const int w = tid >> 6, lane = tid & 63, c = lane & 15, qd = lane >> 4;
    const int wm = w >> 1, wn = w & 1;
    const int c7 = c & 7;                         // row&7 of every frag-read row
    const int m0 = blockIdx.x * 128, n0 = blockIdx.y * 128;
    auto stage = [&](int kt, int buf) {
#pragma unroll
        for (int l = 0; l < 4; ++l) {
            int slot = l * 256 + tid;             // 16B slots: row = slot>>3, chunk = slot&7
            int row = slot >> 3, ch = slot & 7;
            int sch = ch ^ (row & 7);             // inverse-swizzled source, linear dest
            gl_lds16(A + (size_t)(m0 + row) * K + kt * 64 + sch * 8, (char*)As[buf] + (size_t)slot * 16);
            gl_lds16(Bt + (size_t)(n0 + row) * K + kt * 64 + sch * 8, (char*)Bs[buf] + (size_t)slot * 16);
        }
    };
    f32x4 acc[4][4] = {};
    stage(0, 0);                                  // 8 loads
    stage(1, 1);                                  // 8 loads
    for (int kt = 0; kt < NKT; ++kt) {
        const int cur = kt & 1;
        if (kt + 1 < NKT) asm volatile("s_waitcnt vmcnt(8)" ::: "memory");
        else              asm volatile("s_waitcnt vmcnt(0)" ::: "memory");
        __builtin_amdgcn_s_barrier();
        __builtin_amdgcn_sched_barrier(0);
#pragma unroll
        for (int kk = 0; kk < 2; ++kk) {
            const int cs8 = (kk * 4 + qd) ^ c7;   // swizzled chunk for k-slice kk
            bf16x8 af[4], bfr[4];
#pragma unroll
            for (int i = 0; i < 4; ++i)
                af[i] = *(const bf16x8*)&As[cur][(wm * 64 + i * 16 + c) * 64 + cs8 * 8];
#pragma unroll
            for (int j = 0; j < 4; ++j)
                bfr[j] = *(const bf16x8*)&Bs[cur][(wn * 64 + j * 16 + c) * 64 + cs8 * 8];
#pragma unroll
            for (int i = 0; i < 4; ++i)
#pragma unroll
                for (int j = 0; j < 4; ++j)
                    acc[i][j] = __builtin_amdgcn_mfma_f32_16x16x32_bf16(af[i], bfr[j], acc[i][j], 0, 0, 0);
        }
        __builtin_amdgcn_sched_barrier(0);
        __builtin_amdgcn_s_barrier();             // all waves done reading buf cur
        if (kt + 2 < NKT) stage(kt + 2, cur);     // safe overwrite; lands over next tile
    }
    const int mb = m0 + wm * 64;
    const int nb = n0 + wn * 64;   // head-aligned (64): nb>>6 = head
    const int h = nb >> 6;
    if (z == 2) {
        // V: store transposed Vt[b,h,d,s], packing 4 consecutive s per store
#pragma unroll
        for (int i = 0; i < 4; ++i) {
            int m = mb + i * 16 + qd * 4;     // 4 consecutive s at r=0..3, same b
            int b = m >> 11, s = m & 2047;
#pragma unroll
            for (int j = 0; j < 4; ++j) {
                int d = j * 16 + c;
                float bv = bias[nb + d];
                bf16x4v v4;
#pragma unroll
                for (int r = 0; r < 4; ++r) v4[r] = (bf16_t)(acc[i][j][r] + bv);
                *(bf16x4v*)(O + ((size_t)(b * 16 + h) * 64 + d) * 2048 + s) = v4;
            }
        }
    } else {
#pragma unroll
        for (int i = 0; i < 4; ++i)
#pragma unroll
            for (int jh = 0; jh < 2; ++jh) {
                int d1 = jh * 16 + c;                 // [0,32)
                float b1 = bias[nb + d1];
                float b2 = bias[nb + d1 + 32];
#pragma unroll
                for (int r = 0; r < 4; ++r) {
                    int m = mb + i * 16 + qd * 4 + r;
                    int b = m >> 11, s = m & 2047;
                    float v1 = acc[i][jh][r] + b1;
                    float v2 = acc[i][jh + 2][r] + b2;
                    float ct = ctab[s * 32 + d1];
                    float st = stab[s * 32 + d1];
                    size_t base = ((size_t)(b * 16 + h) * 2048 + s) * 64;
                    O[base + d1]      = (bf16_t)((v1 * ct - v2 * st) * scale);
                    O[base + d1 + 32] = (bf16_t)((v2 * ct + v1 * st) * scale);
                }
            }
    }
}

// ---------------- out-proj GEMM: fp32 store [m,n] + bias. Grid (64,8), x = M-tile ----------------
// Same T4-lite counted-vmcnt double-buffer as gemm_qkv.
__global__ __launch_bounds__(256) void gemm_out(const bf16_t* __restrict__ A, const bf16_t* __restrict__ Bt,
                                                const float* __restrict__ bias, float* __restrict__ O) {
    constexpr int K = 1024, N = 1024, NKT = K / 64;
    __shared__ alignas(16) bf16_t As[2][128 * 64];
    __shared__ alignas(16) bf16_t Bs[2][128 * 64];
    const int tid = threadIdx.x;
    const int w = tid >> 6, lane = tid & 63, c = lane & 15, qd = lane >> 4;
    const int wm = w >> 1, wn = w & 1;
    const int c7 = c & 7;
    const int m0 = blockIdx.x * 128, n0 = blockIdx.y * 128;
    auto stage = [&](int kt, int buf) {
#pragma unroll
        for (int l = 0; l < 4; ++l) {
            int slot = l * 256 + tid;
            int row = slot >> 3, ch = slot & 7;
            int sch = ch ^ (row & 7);
            gl_lds16(A + (size_t)(m0 + row) * K + kt * 64 + sch * 8, (char*)As[buf] + (size_t)slot * 16);
            gl_lds16(Bt + (size_t)(n0 + row) * K + kt * 64 + sch * 8, (char*)Bs[buf] + (size_t)slot * 16);
        }
    };
    f32x4 acc[4][4] = {};
    stage(0, 0);
    stage(1, 1);
    for (int kt = 0; kt < NKT; ++kt) {
        const int cur = kt & 1;
        if (kt + 1 < NKT) asm volatile("s_waitcnt vmcnt(8)" ::: "memory");
        else              asm volatile("s_waitcnt vmcnt(0)" ::: "memory");
        __builtin_amdgcn_s_barrier();
        __builtin_amdgcn_sched_barrier(0);
#pragma unroll
        for (int kk = 0; kk < 2; ++kk) {
            const int cs8 = (kk * 4 + qd) ^ c7;
            bf16x8 af[4], bfr[4];
#pragma unroll
            for (int i = 0; i < 4; ++i)
                af[i] = *(const bf16x8*)&As[cur][(wm * 64 + i * 16 + c) * 64 + cs8 * 8];
#pragma unroll
            for (int j = 0; j < 4; ++j)
                bfr[j] = *(const bf16x8*)&Bs[cur][(wn * 64 + j * 16 + c) * 64 + cs8 * 8];
#pragma unroll
            for (int i = 0; i < 4; ++i)
#pragma unroll
                for (int j = 0; j < 4; ++j)
                    acc[i][j] = __builtin_amdgcn_mfma_f32_16x16x32_bf16(af[i], bfr[j], acc[i][j], 0, 0, 0);
        }
        __builtin_amdgcn_sched_barrier(0);
        __builtin_amdgcn_s_barrier();
        if (kt + 2 < NKT) stage(kt + 2, cur);
    }
    const int mb = m0 + wm * 64, nb = n0 + wn * 64;
#pragma unroll
    for (int i = 0; i < 4; ++i)
#pragma unroll
        for (int j = 0; j < 4; ++j) {
            int n = nb + j * 16 + c;
            float bv = bias[n];
#pragma unroll
            for (int r = 0; r < 4; ++r) {
                int m = mb + i * 16 + qd * 4 + r;
                O[(size_t)m * N + n] = acc[i][j][r] + bv;
            }
        }
}

// ---------------- flash attention v13: r9 structure + staging-address hoist ----------------
// (unchanged from r13 — attn left the top-5 with the hoist)
// Grid (64,16): x = bh. 4 blocks/CU, 16 waves/CU. Swapped QK, permlane32 St->PV,
// ones-B-frag row sums, setprio on MFMA clusters, chunk-XOR swizzled LDS.
__global__ __launch_bounds__(256, 4) void attn(const bf16_t* __restrict__ Q, const bf16_t* __restrict__ K,
                                               const bf16_t* __restrict__ Vt, bf16_t* __restrict__ ctx) {
    constexpr int S = 2048;
    __shared__ alignas(16) char smem[32768];   // Q stage 16KB -> [buf][K 8KB | V 8KB] x2
    const int tid = threadIdx.x, w = tid >> 6, lane = tid & 63;
    const int lo5 = lane & 31, hi = lane >> 5;
    const int rm = (lo5 >> 1) & 7;              // read-side swizzle mask (row mod 16)/2
    const int bh = blockIdx.x, q0 = blockIdx.y * 128;
    const bf16_t* Qb = Q + (size_t)bh * S * 64 + (size_t)q0 * 64;
    const bf16_t* Kb = K + (size_t)bh * S * 64;
    const bf16_t* Vb = Vt + (size_t)bh * 64 * S;
    // ---- stage Q (128x64 = 16KB), read B-frags, recycle region ----
#pragma unroll
    for (int l = 0; l < 4; ++l) {
        int slot = l * 256 + tid;               // 16B slots
        int row = slot >> 3, ch = slot & 7;
        int sch = ch ^ ((row >> 1) & 7);
        gl_lds16(Qb + (size_t)row * 64 + sch * 8, smem + (size_t)slot * 16);
    }
    __syncthreads();
    bf16x8 qf[4];                               // [kc]: B[n=q=w*32+lo5][k=d=kc*16+hi*8+j]
    {
        const bf16_t* Qs = (const bf16_t*)smem;
#pragma unroll
        for (int kc = 0; kc < 4; ++kc)
            qf[kc] = *(const bf16x8*)&Qs[(size_t)(w * 32 + lo5) * 64 + ((kc * 2 + hi) ^ rm) * 8];
    }
    __syncthreads();                            // all waves done reading Q
    // ---- per-thread staging bases (affine in kt: K += 4096, V += 64 per window) ----
    const bf16_t* kgp[2];
    const bf16_t* vgp[2];
    char* klp[2];
    char* vlp[2];
#pragma unroll
    for (int l = 0; l < 2; ++l) {
        int slot = l * 256 + tid;
        int row = slot >> 3, ch = slot & 7;
        int sch = ch ^ ((row >> 1) & 7);
        kgp[l] = Kb + (size_t)row * 64 + sch * 8;
        vgp[l] = Vb + (size_t)row * S + sch * 8;
        klp[l] = smem + (size_t)slot * 16;          // + buf*16384
        vlp[l] = smem + 8192 + (size_t)slot * 16;   // + buf*16384
    }
    auto stageKV = [&](int kt, int buf) {
#pragma unroll
        for (int l = 0; l < 2; ++l) {
            gl_lds16(kgp[l] + (size_t)kt * 4096, klp[l] + buf * 16384);
            gl_lds16(vgp[l] + (size_t)kt * 64,   vlp[l] + buf * 16384);
        }
    };
    stageKV(0, 0);
    f32x16 acc_o[2] = {};                       // [db]
    f32x16 acc_l = {};                          // row-sums (all cols equal)
    const f32x16 Z16 = {};
    bf16x8 ones;
    {
        u32x4 ov = {0x3F803F80u, 0x3F803F80u, 0x3F803F80u, 0x3F803F80u};
        ones = __builtin_bit_cast(bf16x8, ov);
    }
    __syncthreads();                            // tile 0 staged
    for (int kt = 0; kt < S / 64; ++kt) {
        const int cur = kt & 1;
        if (kt + 1 < S / 64) stageKV(kt + 1, cur ^ 1);
        const bf16_t* KsC = (const bf16_t*)(smem + cur * 16384);
        const bf16_t* VsC = (const bf16_t*)(smem + cur * 16384 + 8192);
        // St[s][q]: A=K[m=s=sb*32+lo5][k=d], B=Q
        f32x16 st[2];                           // [sb]
        __builtin_amdgcn_s_setprio(1);
#pragma unroll
        for (int kc = 0; kc < 4; ++kc) {
            bf16x8 kf[2];
#pragma unroll
            for (int sb = 0; sb < 2; ++sb)
                kf[sb] = *(const bf16x8*)&KsC[(size_t)(sb * 32 + lo5) * 64 + ((kc * 2 + hi) ^ rm) * 8];
#pragma unroll
            for (int sb = 0; sb < 2; ++sb)
                st[sb] = __builtin_amdgcn_mfma_f32_32x32x16_bf16(kf[sb], qf[kc],
                                                                 kc == 0 ? Z16 : st[sb], 0, 0, 0);
        }
        __builtin_amdgcn_s_setprio(0);
        // p = 2^st, pack s-pairs: pku[sb][u] covers s = sb*32 + 8*(u>>1) + 4*hi + 2*(u&1) + {0,1}
        uint32_t pku[2][8];
#pragma unroll
        for (int sb = 0; sb < 2; ++sb)
#pragma unroll
            for (int u = 0; u < 8; ++u)
                pku[sb][u] = pkbf16(fexp2(st[sb][2 * u]), fexp2(st[sb][2 * u + 1]));
        // PV: A = P[m=q][k=s chunk skc], B = V[n=d][k=s]; plus l via ones B-frag
        __builtin_amdgcn_s_setprio(1);
#pragma unroll
        for (int skc = 0; skc < 4; ++skc) {
            bf16x8 vf[2];
#pragma unroll
            for (int db = 0; db < 2; ++db)
                vf[db] = *(const bf16x8*)&VsC[(size_t)(db * 32 + lo5) * 64 + ((skc * 2 + hi) ^ rm) * 8];
            const int sb = skc >> 1, b = (skc & 1) * 4;
            uint32_t p0 = pku[sb][b + 0], p1 = pku[sb][b + 1];
            uint32_t p2 = pku[sb][b + 2], p3 = pku[sb][b + 3];
#if __has_builtin(__builtin_amdgcn_permlane32_swap)
            u32x2 r02 = __builtin_amdgcn_permlane32_swap(p0, p2, false, false);
            u32x2 r13 = __builtin_amdgcn_permlane32_swap(p1, p3, false, false);
            u32x4 av = {r02[0], r13[0], r02[1], r13[1]};
#else
            uint32_t send0 = hi ? p0 : p2;
            uint32_t send1 = hi ? p1 : p3;
            uint32_t recv0 = __shfl_xor(send0, 32);
            uint32_t recv1 = __shfl_xor(send1, 32);
            u32x4 av = {hi ? recv0 : p0, hi ? recv1 : p1,
                        hi ? p2 : recv0, hi ? p3 : recv1};
#endif
            bf16x8 af = __builtin_bit_cast(bf16x8, av);
            acc_l = __builtin_amdgcn_mfma_f32_32x32x16_bf16(af, ones, acc_l, 0, 0, 0);
#pragma unroll
            for (int db = 0; db < 2; ++db)
                acc_o[db] = __builtin_amdgcn_mfma_f32_32x32x16_bf16(af, vf[db], acc_o[db], 0, 0, 0);
        }
        __builtin_amdgcn_s_setprio(0);
        __syncthreads();
    }
    // epilogue: o = acc_o / acc_l (rows aligned); C row = (reg&3)+8*(reg>>2)+4*hi, col = lo5
    const int b = bh >> 4, h = bh & 15;
    float linv[16];
#pragma unroll
    for (int r = 0; r < 16; ++r) linv[r] = 1.0f / acc_l[r];
#pragma unroll
    for (int db = 0; db < 2; ++db)
#pragma unroll
        for (int r = 0; r < 16; ++r) {
            int qrow = q0 + w * 32 + (r & 3) + 8 * (r >> 2) + 4 * hi;
            int d = db * 32 + lo5;
            float o = acc_o[db][r] * linv[r];
            ctx[((size_t)(b * 2048 + qrow)) * 1024 + (size_t)h * 64 + d] = (bf16_t)o;
        }
}

extern "C" void kernel_launch(void* const* d_in, const int* in_sizes, int n_in,
                              void* d_out, int out_size, void* d_ws, size_t ws_size,
                              hipStream_t stream) {
    (void)in_sizes; (void)n_in; (void)out_size; (void)ws_size;
    const float* query = (const float*)d_in[0];
    const float* key   = (const float*)d_in[1];
    const float* value = (const float*)d_in[2];
    const float* Wq = (const float*)d_in[3];
    const float* bq = (const float*)d_in[4];
    const float* Wk = (const float*)d_in[5];
    const float* bk = (const float*)d_in[6];
    const float* Wv = (const float*)d_in[7];
    const float* bv = (const float*)d_in[8];
    const float* Wo = (const float*)d_in[9];
    const float* bo = (const float*)d_in[10];

    const size_t SZ = (size_t)8192 * 1024;
    bf16_t* Xq = (bf16_t*)d_ws;
    bf16_t* Xk = Xq + SZ;
    bf16_t* Xv = Xk + SZ;
    bf16_t* Qb = Xv + SZ;
    bf16_t* Kb = Qb + SZ;
    bf16_t* Vtb = Kb + SZ;
    bf16_t* Wqt = Vtb + SZ;
    bf16_t* Wkt = Wqt + 1024 * 1024;
    bf16_t* Wvt = Wkt + 1024 * 1024;
    bf16_t* Wot = Wvt + 1024 * 1024;
    float* ctab = (float*)(Wot + 1024 * 1024);
    float* stab = ctab + 2048 * 32;
    bf16_t* CT = Xq;                // alias: Xq dead after projection GEMM

    castk<<<dim3(8192, 3), 256, 0, stream>>>(query, key, value, Xq, Xk, Xv);
    wtrans<<<dim3(32, 32, 4), 256, 0, stream>>>(Wq, Wk, Wv, Wo, Wqt, Wkt, Wvt, Wot);
    rope_tab<<<256, 256, 0, stream>>>(ctab, stab);
    gemm_qkv<<<dim3(64, 8, 3), 256, 0, stream>>>(Xq, Xk, Xv, Wqt, Wkt, Wvt, bq, bk, bv,
                                                 Qb, Kb, Vtb, ctab, stab);
    attn<<<dim3(64, 16), 256, 0, stream>>>(Qb, Kb, Vtb, CT);
    gemm_out<<<dim3(64, 8), 256, 0, stream>>>(CT, Wot, bo, (float*)d_out);
}